// Round 5
// baseline (148.971 us; speedup 1.0000x reference)
//
#include <hip/hip_runtime.h>
#include <math.h>

#define L 250000
#define FEAT 100
#define HID 50
#define HS 165
#define CQ 50257
#define EXTV 1000
#define NOUT (CQ + EXTV)   // 51257
#define NB7 128

#define NBLK23 2048
#define NW23 (NBLK23 * 4)   // 8192 waves

// workspace float offsets
#define WS_Q     0      // 100 floats (16B-aligned: offset 0)
#define WS_P1    100
#define WS_P2    101
#define WS_SCALE 102    // p2/denom
#define WS_DENOM 103
#define WS_CT    104    // 100
#define WS_ET    204    // 200 (16B aligned: 204*4=816=51*16)
#define WS_H     404    // 50
#define WS_E     512    // 250000 (exp(score) per source position)
#define WS_OUT   250624 // 51257 (pre-logsoftmax extended vocab)
#define WS_PM    301952 // 128 partial maxes
#define WS_PS    302080 // 128 partial sums

__device__ __forceinline__ float sigm(float x) { return 1.f / (1.f + expf(-x)); }

// ---------------- K1: LSTM step + q + p1/p2 + accumulator init ----------------
__global__ void k1_lstm(const float* __restrict__ y, const float* __restrict__ h0,
                        const float* __restrict__ c0,
                        const float* __restrict__ W_ih, const float* __restrict__ W_hh,
                        const float* __restrict__ b_ih, const float* __restrict__ b_hh,
                        const float* __restrict__ w_h_W, const float* __restrict__ w_h_b,
                        const float* __restrict__ l3_W, const float* __restrict__ l3_b,
                        const float* __restrict__ l4_W, const float* __restrict__ l4_b,
                        float* __restrict__ ws, float* __restrict__ out) {
    __shared__ float s_y[HS], s_h[HID], s_c[HID], s_g[4 * HID], s_hn[HID];
    int t = threadIdx.x;
    if (t < HS) s_y[t] = y[t];
    if (t < HID) { s_h[t] = h0[t]; s_c[t] = c0[t]; }
    __syncthreads();
    if (t < 4 * HID) {
        float acc = b_ih[t] + b_hh[t];
        const float* wi = W_ih + t * HS;
        for (int k = 0; k < HS; ++k) acc += wi[k] * s_y[k];
        const float* wh = W_hh + t * HID;
        for (int k = 0; k < HID; ++k) acc += wh[k] * s_h[k];
        s_g[t] = acc;
    }
    __syncthreads();
    if (t < HID) {
        float ig = sigm(s_g[t]);
        float fg = sigm(s_g[HID + t]);
        float gg = tanhf(s_g[2 * HID + t]);
        float og = sigm(s_g[3 * HID + t]);
        float cn = fg * s_c[t] + ig * gg;
        float hn = og * tanhf(cn);
        s_hn[t] = hn;
        ws[WS_H + t] = hn;
        out[NOUT + t] = hn;          // h_new output
        out[NOUT + HID + t] = cn;    // c_new output
    }
    __syncthreads();
    if (t < FEAT) {
        float acc = w_h_b[t];
        const float* w = w_h_W + t * HID;
        for (int k = 0; k < HID; ++k) acc += w[k] * s_hn[k];
        ws[WS_Q + t] = acc;
        ws[WS_CT + t] = 0.f;         // zero context accumulator
    }
    if (t == 200) {
        float acc = l3_b[0];
        for (int k = 0; k < HID; ++k) acc += l3_W[k] * s_hn[k];
        ws[WS_P1] = sigm(acc);
    }
    if (t == 201) {
        float acc = l4_b[0];
        for (int k = 0; k < HID; ++k) acc += l4_W[k] * s_hn[k];
        ws[WS_P2] = sigm(acc);
    }
    if (t == 202) ws[WS_DENOM] = 0.f;
}

// ------- K23: wave-per-row register-resident pass over H: e, denom, ct --------
// Lane l owns columns l and l+64. Per row: 2 coalesced loads, butterfly dot,
// e = exp(dot) (uniform across lanes), ct accum from registers. No barriers,
// no LDS tile, 2 rows pipelined.
__global__ void __launch_bounds__(256)
k23_fused(const float* __restrict__ H, const float* __restrict__ ws,
          float* __restrict__ e_out, float* __restrict__ ct,
          float* __restrict__ denom) {
    __shared__ float s_ct[4][FEAT];
    __shared__ float s_d[4];
    int t = threadIdx.x;
    int w = t >> 6, lane = t & 63;
    long wid = (long)blockIdx.x * 4 + w;
    float q0 = ws[WS_Q + lane];
    float q1 = (lane < 36) ? ws[WS_Q + 64 + lane] : 0.f;
    long r0 = (wid * L) / NW23;
    long r1 = ((wid + 1) * L) / NW23;
    float c0a = 0.f, c1a = 0.f, dacc = 0.f;

    long r = r0;
    float h0a = 0.f, h1a = 0.f, h0b = 0.f, h1b = 0.f;
    if (r < r1) {
        const float* p = H + r * FEAT;
        h0a = p[lane]; h1a = (lane < 36) ? p[64 + lane] : 0.f;
    }
    if (r + 1 < r1) {
        const float* p = H + (r + 1) * FEAT;
        h0b = p[lane]; h1b = (lane < 36) ? p[64 + lane] : 0.f;
    }
    for (; r + 2 <= r1; r += 2) {
        float h0c = 0.f, h1c = 0.f, h0d = 0.f, h1d = 0.f;
        if (r + 2 < r1) {
            const float* p = H + (r + 2) * FEAT;
            h0c = p[lane]; h1c = (lane < 36) ? p[64 + lane] : 0.f;
        }
        if (r + 3 < r1) {
            const float* p = H + (r + 3) * FEAT;
            h0d = p[lane]; h1d = (lane < 36) ? p[64 + lane] : 0.f;
        }
        float pa = h0a * q0 + h1a * q1;
        float pb = h0b * q0 + h1b * q1;
#pragma unroll
        for (int o = 1; o < 64; o <<= 1) {
            pa += __shfl_xor(pa, o);
            pb += __shfl_xor(pb, o);
        }
        float ea = expf(pa), eb = expf(pb);
        if (lane == 0) { e_out[r] = ea; e_out[r + 1] = eb; dacc += ea + eb; }
        c0a += ea * h0a + eb * h0b;
        c1a += ea * h1a + eb * h1b;
        h0a = h0c; h1a = h1c; h0b = h0d; h1b = h1d;
    }
    if (r < r1) {   // tail row (already in h0a/h1a)
        float pa = h0a * q0 + h1a * q1;
#pragma unroll
        for (int o = 1; o < 64; o <<= 1) pa += __shfl_xor(pa, o);
        float ea = expf(pa);
        if (lane == 0) { e_out[r] = ea; dacc += ea; }
        c0a += ea * h0a;
        c1a += ea * h1a;
    }
    s_ct[w][lane] = c0a;
    if (lane < 36) s_ct[w][64 + lane] = c1a;
    if (lane == 0) s_d[w] = dacc;
    __syncthreads();
    if (t < FEAT) atomicAdd(&ct[t], s_ct[0][t] + s_ct[1][t] + s_ct[2][t] + s_ct[3][t]);
    if (t == 128) atomicAdd(denom, s_d[0] + s_d[1] + s_d[2] + s_d[3]);
}

// ---------------- K4: c_t /= denom ; e_t = sigmoid(l1) ; scale ----------------
__global__ void k4_et(const float* __restrict__ l1_W, const float* __restrict__ l1_b,
                      float* __restrict__ ws) {
    __shared__ float s_t[150];
    int t = threadIdx.x;
    float denom = ws[WS_DENOM];
    if (t < HID) s_t[t] = ws[WS_H + t];
    if (t < FEAT) s_t[HID + t] = ws[WS_CT + t] / denom;
    if (t == 0) ws[WS_SCALE] = ws[WS_P2] / denom;
    __syncthreads();
    if (t < 200) {
        float acc = l1_b[t];
        const float* w = l1_W + t * 150;
        for (int k = 0; k < 150; ++k) acc += w[k] * s_t[k];
        ws[WS_ET + t] = sigm(acc);
    }
}

// ---------------- K5: out[row] = p1*(l2_W[row].e_t + b) ; ext rows = 0 -------
__global__ void k5_vocab(const float* __restrict__ l2_W, const float* __restrict__ l2_b,
                         const float* __restrict__ ws, float* __restrict__ out) {
    __shared__ float4 s_e[50];
    __shared__ float s_p1;
    int t = threadIdx.x;
    if (t < 50) s_e[t] = ((const float4*)(ws + WS_ET))[t];
    if (t == 255) s_p1 = ws[WS_P1];
    __syncthreads();
    int w = t >> 6, lane = t & 63;
    int row = blockIdx.x * 4 + w;
    if (row < CQ) {
        float acc = 0.f;
        if (lane < 50) {
            float4 a = ((const float4*)l2_W)[(size_t)row * 50 + lane];
            float4 b = s_e[lane];
            acc = a.x * b.x + a.y * b.y + a.z * b.z + a.w * b.w;
        }
        for (int o = 32; o > 0; o >>= 1) acc += __shfl_down(acc, o);
        if (lane == 0) out[row] = s_p1 * (acc + l2_b[row]);
    } else if (row < NOUT) {
        if (lane == 0) out[row] = 0.f;
    }
}

// ---------------- K6: scatter-add pointer attention ----------------
__global__ void k6_scatter(const int* __restrict__ cont, const float* __restrict__ e,
                           const float* __restrict__ ws, float* __restrict__ out) {
    int i = blockIdx.x * blockDim.x + threadIdx.x;
    if (i < L) {
        float scale = ws[WS_SCALE];
        atomicAdd(&out[cont[i]], scale * e[i]);
    }
}

// ---------------- K7a: per-block max & sumexp partials ----------------
__global__ void k7a_partial(const float* __restrict__ outv, float* __restrict__ pm,
                            float* __restrict__ ps) {
    __shared__ float red[4];
    __shared__ float red2[4];
    int t = threadIdx.x;
    int chunk = (NOUT + gridDim.x - 1) / gridDim.x;
    int start = blockIdx.x * chunk;
    int end = min(start + chunk, NOUT);
    float m = -1e30f;
    for (int i = start + t; i < end; i += blockDim.x) m = fmaxf(m, outv[i]);
    for (int o = 32; o > 0; o >>= 1) m = fmaxf(m, __shfl_down(m, o));
    if ((t & 63) == 0) red[t >> 6] = m;
    __syncthreads();
    if (t == 0) red[0] = fmaxf(fmaxf(red[0], red[1]), fmaxf(red[2], red[3]));
    __syncthreads();
    m = red[0];
    float s = 0.f;
    for (int i = start + t; i < end; i += blockDim.x) s += expf(outv[i] - m);
    for (int o = 32; o > 0; o >>= 1) s += __shfl_down(s, o);
    if ((t & 63) == 0) red2[t >> 6] = s;
    __syncthreads();
    if (t == 0) { pm[blockIdx.x] = m; ps[blockIdx.x] = red2[0] + red2[1] + red2[2] + red2[3]; }
}

// ---------------- K7c: combine partials (redundant per thread) + final write --
__global__ void k7c_final(const float* __restrict__ outv, const float* __restrict__ pm,
                          const float* __restrict__ ps, float* __restrict__ dout) {
    int t = threadIdx.x;
    float gm = -1e30f;
    for (int b = 0; b < NB7; ++b) gm = fmaxf(gm, pm[b]);
    float s = 0.f;
    for (int b = 0; b < NB7; ++b) s += ps[b] * expf(pm[b] - gm);
    float lse = gm + logf(s);
    int j = blockIdx.x * blockDim.x + t;
    if (j < NOUT) dout[j] = outv[j] - lse;
}

extern "C" void kernel_launch(void* const* d_in, const int* in_sizes, int n_in,
                              void* d_out, int out_size, void* d_ws, size_t ws_size,
                              hipStream_t stream) {
    const float* H    = (const float*)d_in[0];
    const float* y    = (const float*)d_in[1];
    const float* h0   = (const float*)d_in[2];
    const float* c0   = (const float*)d_in[3];
    const int*   cont = (const int*)d_in[4];
    // d_in[5] = ext scalar (1000), hardcoded
    const float* W_ih = (const float*)d_in[6];
    const float* W_hh = (const float*)d_in[7];
    const float* b_ih = (const float*)d_in[8];
    const float* b_hh = (const float*)d_in[9];
    const float* w_h_W = (const float*)d_in[10];
    const float* w_h_b = (const float*)d_in[11];
    const float* l1_W = (const float*)d_in[12];
    const float* l1_b = (const float*)d_in[13];
    const float* l2_W = (const float*)d_in[14];
    const float* l2_b = (const float*)d_in[15];
    const float* l3_W = (const float*)d_in[16];
    const float* l3_b = (const float*)d_in[17];
    const float* l4_W = (const float*)d_in[18];
    const float* l4_b = (const float*)d_in[19];

    float* ws  = (float*)d_ws;
    float* out = (float*)d_out;

    k1_lstm<<<1, 256, 0, stream>>>(y, h0, c0, W_ih, W_hh, b_ih, b_hh,
                                   w_h_W, w_h_b, l3_W, l3_b, l4_W, l4_b, ws, out);

    k23_fused<<<NBLK23, 256, 0, stream>>>(H, ws, ws + WS_E, ws + WS_CT, ws + WS_DENOM);

    k4_et<<<1, 256, 0, stream>>>(l1_W, l1_b, ws);

    k5_vocab<<<(NOUT + 3) / 4, 256, 0, stream>>>(l2_W, l2_b, ws, ws + WS_OUT);

    k6_scatter<<<(L + 255) / 256, 256, 0, stream>>>(cont, ws + WS_E, ws, ws + WS_OUT);

    k7a_partial<<<NB7, 256, 0, stream>>>(ws + WS_OUT, ws + WS_PM, ws + WS_PS);

    k7c_final<<<(NOUT + 255) / 256, 256, 0, stream>>>(ws + WS_OUT, ws + WS_PM, ws + WS_PS, out);
}

// Round 6
// 93.489 us; speedup vs baseline: 1.5934x; 1.5934x over previous
//
#include <hip/hip_runtime.h>
#include <math.h>

#define L 250000
#define FEAT 100
#define HID 50
#define HS 165
#define CQ 50257
#define EXTV 1000
#define NOUT (CQ + EXTV)   // 51257
#define NB7 128

#define NBLK23 2048
#define NW23 (NBLK23 * 4)   // 8192 waves

// workspace float offsets
#define WS_Q     0      // 100 floats (16B-aligned: offset 0)
#define WS_P1    100
#define WS_P2    101
#define WS_SCALE 102    // p2/denom
#define WS_DENOM 103
#define WS_CT    104    // 100
#define WS_ET    204    // 200 (16B aligned: 204*4=816=51*16)
#define WS_H     404    // 50
#define WS_E     512    // 250000 (exp(score) per source position)
#define WS_OUT   250624 // 51257 (pre-logsoftmax extended vocab)
#define WS_PM    301952 // 128 partial maxes
#define WS_PS    302080 // 128 partial sums
#define WS_PART  302208 // 101 * 2048 partials (transposed: [col][blk])

__device__ __forceinline__ float sigm(float x) { return 1.f / (1.f + expf(-x)); }

// ---------------- K1: LSTM step + q + p1/p2 ----------------
__global__ void k1_lstm(const float* __restrict__ y, const float* __restrict__ h0,
                        const float* __restrict__ c0,
                        const float* __restrict__ W_ih, const float* __restrict__ W_hh,
                        const float* __restrict__ b_ih, const float* __restrict__ b_hh,
                        const float* __restrict__ w_h_W, const float* __restrict__ w_h_b,
                        const float* __restrict__ l3_W, const float* __restrict__ l3_b,
                        const float* __restrict__ l4_W, const float* __restrict__ l4_b,
                        float* __restrict__ ws, float* __restrict__ out) {
    __shared__ float s_y[HS], s_h[HID], s_c[HID], s_g[4 * HID], s_hn[HID];
    int t = threadIdx.x;
    if (t < HS) s_y[t] = y[t];
    if (t < HID) { s_h[t] = h0[t]; s_c[t] = c0[t]; }
    __syncthreads();
    if (t < 4 * HID) {
        float acc = b_ih[t] + b_hh[t];
        const float* wi = W_ih + t * HS;
        for (int k = 0; k < HS; ++k) acc += wi[k] * s_y[k];
        const float* wh = W_hh + t * HID;
        for (int k = 0; k < HID; ++k) acc += wh[k] * s_h[k];
        s_g[t] = acc;
    }
    __syncthreads();
    if (t < HID) {
        float ig = sigm(s_g[t]);
        float fg = sigm(s_g[HID + t]);
        float gg = tanhf(s_g[2 * HID + t]);
        float og = sigm(s_g[3 * HID + t]);
        float cn = fg * s_c[t] + ig * gg;
        float hn = og * tanhf(cn);
        s_hn[t] = hn;
        ws[WS_H + t] = hn;
        out[NOUT + t] = hn;          // h_new output
        out[NOUT + HID + t] = cn;    // c_new output
    }
    __syncthreads();
    if (t < FEAT) {
        float acc = w_h_b[t];
        const float* w = w_h_W + t * HID;
        for (int k = 0; k < HID; ++k) acc += w[k] * s_hn[k];
        ws[WS_Q + t] = acc;
    }
    if (t == 200) {
        float acc = l3_b[0];
        for (int k = 0; k < HID; ++k) acc += l3_W[k] * s_hn[k];
        ws[WS_P1] = sigm(acc);
    }
    if (t == 201) {
        float acc = l4_b[0];
        for (int k = 0; k < HID; ++k) acc += l4_W[k] * s_hn[k];
        ws[WS_P2] = sigm(acc);
    }
}

// ------- K23: wave-per-row register-resident pass over H: e, partials ---------
// Lane l owns columns l and l+64. Per row: 2 coalesced loads, butterfly dot,
// e = exp(dot) (uniform across lanes), ct accum from registers. No barriers
// in the loop, no atomics: per-block partials go to pt[col*NBLK23 + blk].
__global__ void __launch_bounds__(256)
k23_fused(const float* __restrict__ H, const float* __restrict__ ws,
          float* __restrict__ e_out, float* __restrict__ pt) {
    __shared__ float s_ct[4][FEAT];
    __shared__ float s_d[4];
    int t = threadIdx.x;
    int w = t >> 6, lane = t & 63;
    long wid = (long)blockIdx.x * 4 + w;
    float q0 = ws[WS_Q + lane];
    float q1 = (lane < 36) ? ws[WS_Q + 64 + lane] : 0.f;
    long r0 = (wid * L) / NW23;
    long r1 = ((wid + 1) * L) / NW23;
    float c0a = 0.f, c1a = 0.f, dacc = 0.f;

    long r = r0;
    float h0a = 0.f, h1a = 0.f, h0b = 0.f, h1b = 0.f;
    if (r < r1) {
        const float* p = H + r * FEAT;
        h0a = p[lane]; h1a = (lane < 36) ? p[64 + lane] : 0.f;
    }
    if (r + 1 < r1) {
        const float* p = H + (r + 1) * FEAT;
        h0b = p[lane]; h1b = (lane < 36) ? p[64 + lane] : 0.f;
    }
    for (; r + 2 <= r1; r += 2) {
        float h0c = 0.f, h1c = 0.f, h0d = 0.f, h1d = 0.f;
        if (r + 2 < r1) {
            const float* p = H + (r + 2) * FEAT;
            h0c = p[lane]; h1c = (lane < 36) ? p[64 + lane] : 0.f;
        }
        if (r + 3 < r1) {
            const float* p = H + (r + 3) * FEAT;
            h0d = p[lane]; h1d = (lane < 36) ? p[64 + lane] : 0.f;
        }
        float pa = h0a * q0 + h1a * q1;
        float pb = h0b * q0 + h1b * q1;
#pragma unroll
        for (int o = 1; o < 64; o <<= 1) {
            pa += __shfl_xor(pa, o);
            pb += __shfl_xor(pb, o);
        }
        float ea = expf(pa), eb = expf(pb);
        if (lane == 0) { e_out[r] = ea; e_out[r + 1] = eb; dacc += ea + eb; }
        c0a += ea * h0a + eb * h0b;
        c1a += ea * h1a + eb * h1b;
        h0a = h0c; h1a = h1c; h0b = h0d; h1b = h1d;
    }
    if (r < r1) {   // tail row (already in h0a/h1a)
        float pa = h0a * q0 + h1a * q1;
#pragma unroll
        for (int o = 1; o < 64; o <<= 1) pa += __shfl_xor(pa, o);
        float ea = expf(pa);
        if (lane == 0) { e_out[r] = ea; dacc += ea; }
        c0a += ea * h0a;
        c1a += ea * h1a;
    }
    s_ct[w][lane] = c0a;
    if (lane < 36) s_ct[w][64 + lane] = c1a;
    if (lane == 0) s_d[w] = dacc;
    __syncthreads();
    if (t < FEAT)
        pt[(size_t)t * NBLK23 + blockIdx.x] =
            s_ct[0][t] + s_ct[1][t] + s_ct[2][t] + s_ct[3][t];
    if (t == 128)
        pt[(size_t)FEAT * NBLK23 + blockIdx.x] = s_d[0] + s_d[1] + s_d[2] + s_d[3];
}

// ------- K3r: reduce 2048 partials per column (atomic-free) ----------
__global__ void k3r_reduce(const float* __restrict__ pt, float* __restrict__ ws) {
    __shared__ float sw[4];
    int col = blockIdx.x;           // 0..100 (100 = denom)
    int t = threadIdx.x;
    const float* p = pt + (size_t)col * NBLK23;
    float s = 0.f;
#pragma unroll
    for (int k = 0; k < NBLK23 / 256; ++k) s += p[t + k * 256];
#pragma unroll
    for (int o = 1; o < 64; o <<= 1) s += __shfl_xor(s, o);
    if ((t & 63) == 0) sw[t >> 6] = s;
    __syncthreads();
    if (t == 0) {
        float tot = sw[0] + sw[1] + sw[2] + sw[3];
        if (col < FEAT) ws[WS_CT + col] = tot;
        else ws[WS_DENOM] = tot;
    }
}

// ---------------- K4: c_t /= denom ; e_t = sigmoid(l1) ; scale ----------------
__global__ void k4_et(const float* __restrict__ l1_W, const float* __restrict__ l1_b,
                      float* __restrict__ ws) {
    __shared__ float s_t[150];
    int t = threadIdx.x;
    float denom = ws[WS_DENOM];
    if (t < HID) s_t[t] = ws[WS_H + t];
    if (t < FEAT) s_t[HID + t] = ws[WS_CT + t] / denom;
    if (t == 0) ws[WS_SCALE] = ws[WS_P2] / denom;
    __syncthreads();
    if (t < 200) {
        float acc = l1_b[t];
        const float* w = l1_W + t * 150;
        for (int k = 0; k < 150; ++k) acc += w[k] * s_t[k];
        ws[WS_ET + t] = sigm(acc);
    }
}

// ---------------- K5: out[row] = p1*(l2_W[row].e_t + b) ; ext rows = 0 -------
__global__ void k5_vocab(const float* __restrict__ l2_W, const float* __restrict__ l2_b,
                         const float* __restrict__ ws, float* __restrict__ out) {
    __shared__ float4 s_e[50];
    __shared__ float s_p1;
    int t = threadIdx.x;
    if (t < 50) s_e[t] = ((const float4*)(ws + WS_ET))[t];
    if (t == 255) s_p1 = ws[WS_P1];
    __syncthreads();
    int w = t >> 6, lane = t & 63;
    int row = blockIdx.x * 4 + w;
    if (row < CQ) {
        float acc = 0.f;
        if (lane < 50) {
            float4 a = ((const float4*)l2_W)[(size_t)row * 50 + lane];
            float4 b = s_e[lane];
            acc = a.x * b.x + a.y * b.y + a.z * b.z + a.w * b.w;
        }
        for (int o = 32; o > 0; o >>= 1) acc += __shfl_down(acc, o);
        if (lane == 0) out[row] = s_p1 * (acc + l2_b[row]);
    } else if (row < NOUT) {
        if (lane == 0) out[row] = 0.f;
    }
}

// ---------------- K6: scatter-add pointer attention ----------------
__global__ void k6_scatter(const int* __restrict__ cont, const float* __restrict__ e,
                           const float* __restrict__ ws, float* __restrict__ out) {
    int i = blockIdx.x * blockDim.x + threadIdx.x;
    if (i < L) {
        float scale = ws[WS_SCALE];
        atomicAdd(&out[cont[i]], scale * e[i]);
    }
}

// ---------------- K7a: per-block max & sumexp partials ----------------
__global__ void k7a_partial(const float* __restrict__ outv, float* __restrict__ pm,
                            float* __restrict__ ps) {
    __shared__ float red[4];
    __shared__ float red2[4];
    int t = threadIdx.x;
    int chunk = (NOUT + gridDim.x - 1) / gridDim.x;
    int start = blockIdx.x * chunk;
    int end = min(start + chunk, NOUT);
    float m = -1e30f;
    for (int i = start + t; i < end; i += blockDim.x) m = fmaxf(m, outv[i]);
    for (int o = 32; o > 0; o >>= 1) m = fmaxf(m, __shfl_down(m, o));
    if ((t & 63) == 0) red[t >> 6] = m;
    __syncthreads();
    if (t == 0) red[0] = fmaxf(fmaxf(red[0], red[1]), fmaxf(red[2], red[3]));
    __syncthreads();
    m = red[0];
    float s = 0.f;
    for (int i = start + t; i < end; i += blockDim.x) s += expf(outv[i] - m);
    for (int o = 32; o > 0; o >>= 1) s += __shfl_down(s, o);
    if ((t & 63) == 0) red2[t >> 6] = s;
    __syncthreads();
    if (t == 0) { pm[blockIdx.x] = m; ps[blockIdx.x] = red2[0] + red2[1] + red2[2] + red2[3]; }
}

// ---------------- K7c: combine partials (redundant per thread) + final write --
__global__ void k7c_final(const float* __restrict__ outv, const float* __restrict__ pm,
                          const float* __restrict__ ps, float* __restrict__ dout) {
    int t = threadIdx.x;
    float gm = -1e30f;
    for (int b = 0; b < NB7; ++b) gm = fmaxf(gm, pm[b]);
    float s = 0.f;
    for (int b = 0; b < NB7; ++b) s += ps[b] * expf(pm[b] - gm);
    float lse = gm + logf(s);
    int j = blockIdx.x * blockDim.x + t;
    if (j < NOUT) dout[j] = outv[j] - lse;
}

extern "C" void kernel_launch(void* const* d_in, const int* in_sizes, int n_in,
                              void* d_out, int out_size, void* d_ws, size_t ws_size,
                              hipStream_t stream) {
    const float* H    = (const float*)d_in[0];
    const float* y    = (const float*)d_in[1];
    const float* h0   = (const float*)d_in[2];
    const float* c0   = (const float*)d_in[3];
    const int*   cont = (const int*)d_in[4];
    // d_in[5] = ext scalar (1000), hardcoded
    const float* W_ih = (const float*)d_in[6];
    const float* W_hh = (const float*)d_in[7];
    const float* b_ih = (const float*)d_in[8];
    const float* b_hh = (const float*)d_in[9];
    const float* w_h_W = (const float*)d_in[10];
    const float* w_h_b = (const float*)d_in[11];
    const float* l1_W = (const float*)d_in[12];
    const float* l1_b = (const float*)d_in[13];
    const float* l2_W = (const float*)d_in[14];
    const float* l2_b = (const float*)d_in[15];
    const float* l3_W = (const float*)d_in[16];
    const float* l3_b = (const float*)d_in[17];
    const float* l4_W = (const float*)d_in[18];
    const float* l4_b = (const float*)d_in[19];

    float* ws  = (float*)d_ws;
    float* out = (float*)d_out;

    k1_lstm<<<1, 256, 0, stream>>>(y, h0, c0, W_ih, W_hh, b_ih, b_hh,
                                   w_h_W, w_h_b, l3_W, l3_b, l4_W, l4_b, ws, out);

    k23_fused<<<NBLK23, 256, 0, stream>>>(H, ws, ws + WS_E, ws + WS_PART);

    k3r_reduce<<<FEAT + 1, 256, 0, stream>>>(ws + WS_PART, ws);

    k4_et<<<1, 256, 0, stream>>>(l1_W, l1_b, ws);

    k5_vocab<<<(NOUT + 3) / 4, 256, 0, stream>>>(l2_W, l2_b, ws, ws + WS_OUT);

    k6_scatter<<<(L + 255) / 256, 256, 0, stream>>>(cont, ws + WS_E, ws, ws + WS_OUT);

    k7a_partial<<<NB7, 256, 0, stream>>>(ws + WS_OUT, ws + WS_PM, ws + WS_PS);

    k7c_final<<<(NOUT + 255) / 256, 256, 0, stream>>>(ws + WS_OUT, ws + WS_PM, ws + WS_PS, out);
}